// Round 9
// baseline (431.477 us; speedup 1.0000x reference)
//
#include <hip/hip_runtime.h>
#include <hip/hip_bf16.h>
#include <math.h>

#define D_MODEL 1024
#define SEQ     1024
#define BATCH   4
#define NHEADS  16
#define HD      64

// log2(e) folds: p = exp2(s') with s' = (q.k)*0.125*log2e + 0.05*log2e*vimp
// (kimp term is constant per q-row -> cancels in softmax; dropped entirely)
#define QSC 0.18033688f   // 0.125 * log2(e)
#define BSC 0.072134752f  // 0.05  * log2(e)

typedef __bf16 bf16x8 __attribute__((ext_vector_type(8)));
typedef __bf16 bf16x4 __attribute__((ext_vector_type(4)));
typedef float  f32x4  __attribute__((ext_vector_type(4)));

__device__ __forceinline__ f32x4 mfma16(bf16x8 a, bf16x8 b, f32x4 c) {
  return __builtin_amdgcn_mfma_f32_16x16x32_bf16(a, b, c, 0, 0, 0);
}

// async global->LDS, 16B per lane; LDS dest = wave-uniform base + lane*16
__device__ __forceinline__ void async16(__bf16* lds, const __bf16* g) {
  __builtin_amdgcn_global_load_lds(g, lds, 16, 0, 0);
}

// ------------------------------------------ fused prep: cvt x, cvt weights, vimp
__global__ __launch_bounds__(256) void prep_kernel(
    const float* __restrict__ x,
    const float* __restrict__ Wq, const float* __restrict__ Wk,
    const float* __restrict__ Wv, const float* __restrict__ Wo,
    const float* __restrict__ v_ema,
    const float* __restrict__ Wimp, const float* __restrict__ bimp,
    __bf16* __restrict__ x_bf, __bf16* __restrict__ wq_bf, __bf16* __restrict__ wk_bf,
    __bf16* __restrict__ wv_bf, __bf16* __restrict__ wo_bf,
    float* __restrict__ vimp) {
  const int bid = blockIdx.x;
  const int tid = threadIdx.x;
  if (bid < 4096) {                       // x: 4M floats = 1M float4
    int i = bid * 256 + tid;
    float4 v = ((const float4*)x)[i];
    bf16x4 o; o[0] = (__bf16)v.x; o[1] = (__bf16)v.y; o[2] = (__bf16)v.z; o[3] = (__bf16)v.w;
    ((bf16x4*)x_bf)[i] = o;
  } else if (bid < 8192) {                // 4 weight mats: 4 x 256K float4
    int i = (bid - 4096) * 256 + tid;
    int sel = i >> 18;
    int j = i & 262143;
    const float* s = (sel == 0) ? Wq : (sel == 1) ? Wk : (sel == 2) ? Wv : Wo;
    __bf16* d      = (sel == 0) ? wq_bf : (sel == 1) ? wk_bf : (sel == 2) ? wv_bf : wo_bf;
    float4 v = ((const float4*)s)[j];
    bf16x4 o; o[0] = (__bf16)v.x; o[1] = (__bf16)v.y; o[2] = (__bf16)v.z; o[3] = (__bf16)v.w;
    ((bf16x4*)d)[j] = o;
  } else {                                // vimp: one wave per (h,s), 16384 waves
    int gw   = (bid - 8192) * 4 + (tid >> 6);
    int lane = tid & 63;
    int h = gw >> 10, s = gw & 1023;
    float sum = 0.f;
    for (int d = lane; d < D_MODEL; d += 64)
      sum += v_ema[s * D_MODEL + d] * Wimp[h * D_MODEL + d];
    for (int mm = 32; mm >= 1; mm >>= 1) sum += __shfl_xor(sum, mm);
    if (lane == 0) vimp[h * SEQ + s] = sum + bimp[h];
  }
}

// ---------------------------------------------------- C = (A[M,K]·W[N,K]^T + bias)
// 128 x (NI*32) tile, BK=32, global_load_lds width-16, swizzled LDS, XCD-aware
// 1-D block decode (each XCD owns a compact L2-resident region).
// NZ==3: z=0 Q (scaled sc0), z=1 K transposed product -> Kp[bh][key][64] rotated,
//        z=2 V -> Vp[bh][key>>6][d][64] rotated.
template<int NI, int NZ, bool OUT_BF16>
__global__ __launch_bounds__(256, 2) void gemm_tile(
    const __bf16* __restrict__ A,
    const __bf16* __restrict__ W0, const __bf16* __restrict__ W1, const __bf16* __restrict__ W2,
    const float* __restrict__ b0, const float* __restrict__ b1, const float* __restrict__ b2,
    void* out0, void* out1, void* out2, float sc0) {
  // ---- XCD-aware decode ----
  const int bid = blockIdx.x;
  const int xcd = bid & 7, wk = bid >> 3;
  int z, row_t, col_t;
  if (NZ == 3) {              // 384 blocks: XCD owns 8 row-tiles x 2 col-tiles x 3z
    z = wk % 3;
    const int t = wk / 3;     // 0..15
    row_t = (xcd >> 1) * 8 + (t >> 1);
    col_t = (xcd & 1) * 2 + (t & 1);
  } else {                    // 256 blocks: XCD owns 4 row-tiles x all 8 col-tiles
    z = 0;
    row_t = xcd * 4 + (wk & 3);
    col_t = wk >> 2;
  }
  const int row0 = row_t * 128;
  const int col0 = col_t * (NI * 32);

  const __bf16* W   = (z == 0) ? W0 : (z == 1) ? W1 : W2;
  const float* bias = (z == 0) ? b0 : (z == 1) ? b1 : b2;
  void* out         = (z == 0) ? out0 : (z == 1) ? out1 : out2;
  const float sc    = (z == 0) ? sc0 : 1.0f;

  __shared__ __bf16 As[128 * 32];
  __shared__ __bf16 Bs[NI * 32 * 32];

  const int tid = threadIdx.x;
  const int w = tid >> 6, l = tid & 63;
  const int quad = l >> 4, l16 = l & 15;
  const int wy = w >> 1, wx = w & 1;

  const f32x4 fzero = {0.f, 0.f, 0.f, 0.f};
  f32x4 acc[4][NI];
  for (int i = 0; i < 4; i++)
    for (int j = 0; j < NI; j++) acc[i][j] = fzero;

  const int lr = l >> 2;                         // 0..15
  const int sw0 = (((l & 3) ^ (lr & 3)) * 8);    // source k offset (swizzled)
  const int rowA = w * 16 + lr;
  const __bf16* aptr = A + (size_t)(row0 + rowA) * D_MODEL + sw0;
  const __bf16* bptr = W + (size_t)(col0 + rowA) * D_MODEL + sw0;
  __bf16* lA0 = &As[w * 512 + l * 8];
  __bf16* lA1 = &As[2048 + w * 512 + l * 8];

  const int rswz = (quad ^ (l16 & 3)) * 8;

  for (int k0 = 0; k0 < D_MODEL; k0 += 32) {
    async16(lA0, aptr + k0);
    async16(lA1, aptr + (size_t)64 * D_MODEL + k0);
    #pragma unroll
    for (int i = 0; i < NI / 2; i++)
      async16(&Bs[i * 2048 + w * 512 + l * 8], bptr + (size_t)(i * 64) * D_MODEL + k0);
    __syncthreads();
    bf16x8 af[4], bfr[NI];
    #pragma unroll
    for (int mi = 0; mi < 4; mi++) af[mi]  = *(const bf16x8*)&As[(wy * 64 + mi * 16 + l16) * 32 + rswz];
    #pragma unroll
    for (int ni = 0; ni < NI; ni++) bfr[ni] = *(const bf16x8*)&Bs[(wx * (NI * 16) + ni * 16 + l16) * 32 + rswz];
    if (NZ == 3 && z == 1) {
      #pragma unroll
      for (int mi = 0; mi < 4; mi++)
        #pragma unroll
        for (int ni = 0; ni < NI; ni++)
          acc[mi][ni] = mfma16(bfr[ni], af[mi], acc[mi][ni]);   // transposed product
    } else {
      #pragma unroll
      for (int mi = 0; mi < 4; mi++)
        #pragma unroll
        for (int ni = 0; ni < NI; ni++)
          acc[mi][ni] = mfma16(af[mi], bfr[ni], acc[mi][ni]);
    }
    __syncthreads();
  }

  if (NZ == 3 && OUT_BF16 && z == 1) {
    // D[wcol][token]: pack 4 hd dims per uint2, rotated within the 64-dim row
    __bf16* kp = (__bf16*)out;
    #pragma unroll
    for (int ni = 0; ni < NI; ni++) {
      const int wcolbase = col0 + wx * (NI * 16) + ni * 16 + quad * 4;
      const float4 b4 = *(const float4*)&bias[wcolbase];
      const float bb[4] = {b4.x, b4.y, b4.z, b4.w};
      #pragma unroll
      for (int mi = 0; mi < 4; mi++) {
        const int token = row0 + wy * 64 + mi * 16 + l16;
        const int bh = (token >> 10) * 16 + (wcolbase >> 6);
        const int colp = ((wcolbase & 63) + ((token & 7) << 3)) & 63;   // rotation
        union { __bf16 hh[4]; uint2 uu; } pk;
        #pragma unroll
        for (int r = 0; r < 4; r++) pk.hh[r] = (__bf16)(acc[mi][ni][r] + bb[r]);
        *(uint2*)(kp + ((size_t)bh * SEQ + (token & 1023)) * HD + colp) = pk.uu;
      }
    }
  } else if (NZ == 3 && OUT_BF16 && z == 2) {
    // chunk-packed Vp[bh][token>>6][d][token'], rotated in key dim
    __bf16* vp = (__bf16*)out;
    #pragma unroll
    for (int ni = 0; ni < NI; ni++) {
      const int col = col0 + wx * (NI * 16) + ni * 16 + l16;   // d (model dim)
      const float bv = bias[col];
      #pragma unroll
      for (int mi = 0; mi < 4; mi++) {
        const int token = row0 + wy * 64 + mi * 16 + quad * 4;
        const int bh = (token >> 10) * 16 + (col >> 6);
        const int chk = (token >> 6) & 15;
        const int keyp = ((token & 63) + ((col & 7) << 3)) & 63;        // rotation
        const size_t base = (((size_t)bh * 16 + chk) * 64 + (col & 63)) * 64 + keyp;
        union { __bf16 hh[4]; uint2 uu; } pk;
        #pragma unroll
        for (int r = 0; r < 4; r++) pk.hh[r] = (__bf16)(acc[mi][ni][r] + bv);
        *(uint2*)(vp + base) = pk.uu;
      }
    }
  } else {
    #pragma unroll
    for (int ni = 0; ni < NI; ni++) {
      const int col = col0 + wx * (NI * 16) + ni * 16 + l16;
      const float bv = bias[col];
      #pragma unroll
      for (int mi = 0; mi < 4; mi++) {
        const int row = row0 + wy * 64 + mi * 16 + quad * 4;
        #pragma unroll
        for (int r = 0; r < 4; r++) {
          float v = (acc[mi][ni][r] + bv) * sc;
          if (OUT_BF16) ((__bf16*)out)[(size_t)(row + r) * D_MODEL + col] = (__bf16)v;
          else          ((float*)out)[(size_t)(row + r) * D_MODEL + col] = v;
        }
      }
    }
  }
}

// ------------------------------------------------------- attention, DMA-staged (m97-style)
// Block = 4 waves = 64 q-rows of one (bh, group). K+V 64-key chunk (16 KB) DMA'd into
// double-buffered LDS via global_load_lds; ONE barrier per chunk. All frag reads are
// ds_read_b128, bank-uniform thanks to the global-side row rotation.
// Snake pairing {g, 15-g}: every block runs exactly 17 chunks.
__global__ __launch_bounds__(256, 2) void attn_kernel(
    const __bf16* __restrict__ Qb, const __bf16* __restrict__ Kp,
    const __bf16* __restrict__ Vp, const float* __restrict__ vimp,
    __bf16* __restrict__ Ob) {
  const int id = blockIdx.x;
  const int bh = id & 63;                 // CU c hosts ids c, c+256 -> same bh: L2 share
  const int gg = id >> 6;                 // 0..7
  const int b = bh >> 4, h = bh & 15;
  const int tid = threadIdx.x;
  const int wave = tid >> 6, lane = tid & 63;
  const int quad = lane >> 4, l16 = lane & 15;

  __shared__ __bf16 Kl[2][4096];          // 64 keys x 64 dims (rotated rows)
  __shared__ __bf16 Vl[2][4096];          // 64 dims x 64 keys (rotated rows)
  __shared__ __bf16 Ps[4][16][72];

  const __bf16* kbase = Kp + (size_t)bh * (SEQ * HD);
  const __bf16* vbase = Vp + (size_t)bh * (SEQ * HD);
  const float* vimpH = vimp + h * SEQ;

  const int rot0 = ((quad + (l16 & 7)) & 7) * 8;        // logical cols quad*8..+7
  const int rot1 = ((quad + 4 + (l16 & 7)) & 7) * 8;    // logical cols 32+quad*8..+7
  const int frow = l16 * 64;

  #pragma unroll 1
  for (int grp = 0; grp < 2; grp++) {
    const int g = grp ? (15 - gg) : gg;
    const int nch = g + 1;
    const int qrow = g * 64 + wave * 16 + l16;
    const __bf16* qp = Qb + (size_t)(b * SEQ + qrow) * D_MODEL + h * HD;
    bf16x8 qa0 = *(const bf16x8*)(qp + quad * 8);        // Q pre-scaled by QSC in gemm
    bf16x8 qa1 = *(const bf16x8*)(qp + 32 + quad * 8);
    float l_i = 0.f;
    f32x4 o[4];
    #pragma unroll
    for (int td = 0; td < 4; td++) { o[td][0] = 0.f; o[td][1] = 0.f; o[td][2] = 0.f; o[td][3] = 0.f; }

    __syncthreads();                      // bufs free of previous group's readers
    async16(&Kl[0][tid * 8], kbase + tid * 8);
    async16(&Kl[0][2048 + tid * 8], kbase + 2048 + tid * 8);
    async16(&Vl[0][tid * 8], vbase + tid * 8);
    async16(&Vl[0][2048 + tid * 8], vbase + 2048 + tid * 8);

    for (int ch = 0; ch < nch; ch++) {
      const int buf = ch & 1;
      __syncthreads();                    // drains DMA for buf (issued ~1 chunk ago)
      if (ch + 1 < nch) {                 // prefetch next chunk into other buffer
        const __bf16* gk = kbase + (ch + 1) * 4096;
        const __bf16* gv = vbase + (ch + 1) * 4096;
        const int nb = buf ^ 1;
        async16(&Kl[nb][tid * 8], gk + tid * 8);
        async16(&Kl[nb][2048 + tid * 8], gk + 2048 + tid * 8);
        async16(&Vl[nb][tid * 8], gv + tid * 8);
        async16(&Vl[nb][2048 + tid * 8], gv + 2048 + tid * 8);
      }
      const int kc = ch * 64;
      float4 vi[4];
      #pragma unroll
      for (int t = 0; t < 4; t++) vi[t] = *(const float4*)(vimpH + kc + t * 16 + quad * 4);
      bf16x8 kf0[4], kf1[4];
      #pragma unroll
      for (int t = 0; t < 4; t++) {
        kf0[t] = *(const bf16x8*)&Kl[buf][t * 1024 + frow + rot0];
        kf1[t] = *(const bf16x8*)&Kl[buf][t * 1024 + frow + rot1];
      }
      bf16x8 vfr0[4], vfr1[4];
      #pragma unroll
      for (int td = 0; td < 4; td++) {
        vfr0[td] = *(const bf16x8*)&Vl[buf][td * 1024 + frow + rot0];
        vfr1[td] = *(const bf16x8*)&Vl[buf][td * 1024 + frow + rot1];
      }
      const f32x4 fz = {0.f, 0.f, 0.f, 0.f};
      float p[4][4];
      float lsum = 0.f;
      #pragma unroll
      for (int t = 0; t < 4; t++) {
        f32x4 sacc = fz;
        sacc = mfma16(kf0[t], qa0, sacc);
        sacc = mfma16(kf1[t], qa1, sacc);
        const float vib[4] = {vi[t].x, vi[t].y, vi[t].z, vi[t].w};
        #pragma unroll
        for (int r = 0; r < 4; r++) {
          float pp = exp2f(sacc[r] + BSC * vib[r]);
          pp = (kc + t * 16 + quad * 4 + r <= qrow) ? pp : 0.f;   // causal (full chunks pass)
          p[t][r] = pp;
          lsum += pp;
        }
      }
      l_i += lsum;
      #pragma unroll
      for (int t = 0; t < 4; t++) {
        union { __bf16 hh[4]; uint2 uu; } pk;
        #pragma unroll
        for (int r = 0; r < 4; r++) pk.hh[r] = (__bf16)p[t][r];
        *(uint2*)&Ps[wave][l16][t * 16 + quad * 4] = pk.uu;
      }
      bf16x8 pf0 = *(const bf16x8*)&Ps[wave][l16][quad * 8];
      bf16x8 pf1 = *(const bf16x8*)&Ps[wave][l16][32 + quad * 8];
      #pragma unroll
      for (int td = 0; td < 4; td++) {
        o[td] = mfma16(vfr0[td], pf0, o[td]);
        o[td] = mfma16(vfr1[td], pf1, o[td]);
      }
    }

    float L = l_i;
    L += __shfl_xor(L, 16);
    L += __shfl_xor(L, 32);
    const float il = 1.0f / L;
    __bf16* op = Ob + (size_t)(b * SEQ + qrow) * D_MODEL + h * HD;
    #pragma unroll
    for (int td = 0; td < 4; td++) {
      union { __bf16 hh[4]; uint2 uu; } pk;
      #pragma unroll
      for (int r = 0; r < 4; r++) pk.hh[r] = (__bf16)(o[td][r] * il);
      *(uint2*)(op + td * 16 + quad * 4) = pk.uu;
    }
  }
}

// ---------------------------------------------------------------------------
extern "C" void kernel_launch(void* const* d_in, const int* in_sizes, int n_in,
                              void* d_out, int out_size, void* d_ws, size_t ws_size,
                              hipStream_t stream) {
  const float* x     = (const float*)d_in[0];
  const float* Wq    = (const float*)d_in[1];
  const float* bq    = (const float*)d_in[2];
  const float* Wk    = (const float*)d_in[3];
  const float* bk    = (const float*)d_in[4];
  const float* Wv    = (const float*)d_in[5];
  const float* bv    = (const float*)d_in[6];
  const float* Wo    = (const float*)d_in[7];
  const float* bo    = (const float*)d_in[8];
  const float* Wimp  = (const float*)d_in[9];
  const float* bimp  = (const float*)d_in[10];
  // d_in[11] = k_ema (unused: kimp bias is per-q-row constant, cancels in softmax)
  const float* v_ema = (const float*)d_in[12];
  float* out = (float*)d_out;

  char* ws = (char*)d_ws;
  __bf16* x_bf  = (__bf16*)(ws);                        // 8 MB
  __bf16* wq_bf = (__bf16*)(ws + (8ull  << 20));        // 2 MB each
  __bf16* wk_bf = (__bf16*)(ws + (10ull << 20));
  __bf16* wv_bf = (__bf16*)(ws + (12ull << 20));
  __bf16* wo_bf = (__bf16*)(ws + (14ull << 20));
  __bf16* q_bf  = (__bf16*)(ws + (16ull << 20));        // 8 MB each
  __bf16* kp_bf = (__bf16*)(ws + (24ull << 20));        // K packed+rotated [bh][key][64]
  __bf16* vp_bf = (__bf16*)(ws + (32ull << 20));        // V packed+rotated [bh][ch][d][64]
  __bf16* a_bf  = (__bf16*)(ws + (40ull << 20));
  float*  vimp  = (float*)(ws + (48ull << 20));         // 64 KB

  prep_kernel<<<12288, 256, 0, stream>>>(
      x, Wq, Wk, Wv, Wo, v_ema, Wimp, bimp,
      x_bf, wq_bf, wk_bf, wv_bf, wo_bf, vimp);

  // Q,K,V projections: 128x256 tiles, XCD-swizzled 1-D grid (384 blocks)
  gemm_tile<8, 3, true><<<dim3(384), 256, 0, stream>>>(
      x_bf, wq_bf, wk_bf, wv_bf, bq, bk, bv,
      (void*)q_bf, (void*)kp_bf, (void*)vp_bf, QSC);

  attn_kernel<<<dim3(512), 256, 0, stream>>>(
      q_bf, kp_bf, vp_bf, vimp, a_bf);

  // out projection: 128x128 tiles, XCD-swizzled (256 blocks), fp32 out
  gemm_tile<4, 1, false><<<dim3(256), 256, 0, stream>>>(
      a_bf, wo_bf, wo_bf, wo_bf, bo, bo, bo,
      (void*)out, (void*)out, (void*)out, 1.0f);
}